// Round 5
// baseline (892.780 us; speedup 1.0000x reference)
//
#include <hip/hip_runtime.h>
#include <stdint.h>

// Problem constants
#define NB 768          // ntiles*N*f = 16*8*6 rows
#define LTILE 334       // positions per row
#define LOUT 315        // 334 - 20 + 1
#define KF 20           // motif length
#define AA 21           // alphabet
#define UU 600          // profiles
#define S_SIZE 76800    // 16*8*600
#define R_SIZE 252000   // 20*21*600
#define NROWS 420       // KF*AA table rows

// workspace layout (bytes)
#define WS_IDS_OFF 504064                    // after Rb (252000*2 -> pad)
#define WS_PS_OFF  (504064 + 258112)         // after ids (768*336 + 64 pad)
// pS2: [768][4 waves][600] f32 = 7,372,800 B

typedef float v2f __attribute__((ext_vector_type(2)));

// ---------------- kernel 1: R = log(max(P/Q, eps)), fp32 out + bf16 copy ---
__global__ __launch_bounds__(256) void prep_R(const float* __restrict__ P,
                                              const float* __restrict__ Q,
                                              float* __restrict__ Rout,
                                              uint16_t* __restrict__ Rb) {
  int i = blockIdx.x * 256 + threadIdx.x;
  if (i >= R_SIZE) return;
  int a = (i / UU) % AA;
  float v = logf(fmaxf(P[i] / Q[a], 1e-6f));
  Rout[i] = v;
  uint32_t x = __float_as_uint(v);
  uint32_t r = (x + 0x7fffu + ((x >> 16) & 1u)) >> 16;
  Rb[i] = (uint16_t)r;
}

// ---------------- kernel 2: one-hot -> letter ids (bytes, rows padded 336) -
__global__ __launch_bounds__(256) void prep_ids(const float* __restrict__ X,
                                                uint8_t* __restrict__ ids) {
  int b = blockIdx.x;
  for (int pos = threadIdx.x; pos < 336; pos += 256) {
    uint8_t id = 0;
    if (pos < LTILE) {
      const float* xp = X + ((size_t)b * LTILE + pos) * AA;
#pragma unroll
      for (int a = 0; a < AA; a++)
        if (xp[a] > 0.5f) id = (uint8_t)a;
    }
    ids[b * 336 + pos] = id;  // bytes 334/335 -> 0 (window padding)
  }
}

// ---- staging helpers: group g covers u0 = g*64, NSEG segments of 8 u ------
// unit i (16 B) -> row = i/NSEG, seg = i%NSEG; LDS addr = row*128 + seg*16
// (row stride fixed at 128 B so the gather layout is identical for the tail).
template <int NSEG>
__device__ __forceinline__ void issue_loads(const uint16_t* __restrict__ Rb,
                                            int u0, int tid, uint4 (&pref)[14]) {
#pragma unroll
  for (int k = 0; k < 14; k++) {
    int i = tid + k * 256;
    if (i < NROWS * NSEG) {
      int row, s;
      if (NSEG == 8) {
        row = i >> 3; s = i & 7;
      } else {
        row = (i * 0x5556) >> 16;  // i/3, exact for i < 49k
        s = i - row * 3;
      }
      pref[k] = *(const uint4*)(Rb + row * UU + u0 + s * 8);
    }
  }
}

template <int NSEG>
__device__ __forceinline__ void write_lds(uint16_t* Tl, int tid,
                                          const uint4 (&pref)[14]) {
#pragma unroll
  for (int k = 0; k < 14; k++) {
    int i = tid + k * 256;
    if (i < NROWS * NSEG) {
      int row, s;
      if (NSEG == 8) {
        row = i >> 3; s = i & 7;
      } else {
        row = (i * 0x5556) >> 16;
        s = i - row * 3;
      }
      *(uint4*)((char*)Tl + row * 128 + s * 16) = pref[k];
    }
  }
}

// ---------------- kernel 3: persistent Z gather, u-fast lane mapping -------
// grid = 768 blocks (3/CU, one scheduling round); block = 4 waves.
// Each block loops all 10 u-groups; staging for group g+1 is prefetched into
// 14 uint4 registers during group g's compute (latency hidden), so the group
// boundary is just {barrier, 14 ds_writes, barrier}.
// Wave lane map: seg = lane&7 (8-u chunk), lrow = lane>>3 (l row).
// LDS table Tl[420][64] bf16 = 53,760 B -> 3 blocks/CU.
// Per-wave partial maxes go straight to pS2[b][wave][u] (no cross-wave LDS
// reduce, no Tl reuse, one fewer barrier); finalS folds waves and f.
__global__ __launch_bounds__(256, 3) void zmain(const uint16_t* __restrict__ Rb,
                                                const uint8_t* __restrict__ ids,
                                                float* __restrict__ Z,
                                                float* __restrict__ pS2) {
  __shared__ __align__(16) uint16_t Tl[NROWS * 64];  // 53,760 B
  int b = blockIdx.x;
  int tid = threadIdx.x;
  int wave = tid >> 6;
  int lane = tid & 63;
  int seg = lane & 7;
  int lrow = lane >> 3;
  const uint8_t* idb = ids + b * 336;
  const char* Tseg = (const char*)Tl + seg * 16;   // + c*128 + w*2688

  uint4 pref[14];
  issue_loads<8>(Rb, 0, tid, pref);   // prologue: group 0

  for (int ug = 0; ug < 10; ug++) {
    int nseg = (ug < 9) ? 8 : 3;     // uw = 64, tail 24
    int u0 = ug * 64;

    __syncthreads();                 // all waves done reading previous table
    if (nseg == 8) write_lds<8>(Tl, tid, pref);
    else           write_lds<3>(Tl, tid, pref);
    // issue next group's loads now; they complete during compute below
    if (ug + 1 < 9)       issue_loads<8>(Rb, u0 + 64, tid, pref);
    else if (ug + 1 == 9) issue_loads<3>(Rb, u0 + 64, tid, pref);
    __syncthreads();                 // table ready

    bool segok = seg < nseg;

    v2f sm[4];
#pragma unroll
    for (int d = 0; d < 4; d++) sm[d] = (v2f){-3.4e38f, -3.4e38f};

    for (int pass = 0; pass < 10; pass++) {
      int l = pass * 32 + wave * 8 + lrow;
      if (l < LOUT && segok) {
        // window bytes ids[l..l+19]: 6 aligned dwords + 64-bit funnel shift
        int al = l & ~3;
        int sh = (l & 3) * 8;
        const uint32_t* wp = (const uint32_t*)(idb + al);
        uint32_t raw[6];
#pragma unroll
        for (int j = 0; j < 6; j++) raw[j] = wp[j];
        uint32_t W[5];
#pragma unroll
        for (int j = 0; j < 5; j++)
          W[j] = (uint32_t)((((uint64_t)raw[j + 1] << 32) | raw[j]) >> sh);

        v2f acc[4];
#pragma unroll
        for (int d = 0; d < 4; d++) acc[d] = (v2f){0.0f, 0.0f};

#pragma unroll
        for (int w = 0; w < KF; w++) {
          uint32_t c = (W[w >> 2] >> ((w & 3) * 8)) & 0xFFu;
          // byte addr = seg*16 + c*128 + (imm) w*2688  (max 53,744 < 64 KB)
          const uint4 rv = *(const uint4*)(Tseg + (c << 7) + w * 2688);
          acc[0] += (v2f){__uint_as_float(rv.x << 16),
                          __uint_as_float(rv.x & 0xffff0000u)};
          acc[1] += (v2f){__uint_as_float(rv.y << 16),
                          __uint_as_float(rv.y & 0xffff0000u)};
          acc[2] += (v2f){__uint_as_float(rv.z << 16),
                          __uint_as_float(rv.z & 0xffff0000u)};
          acc[3] += (v2f){__uint_as_float(rv.w << 16),
                          __uint_as_float(rv.w & 0xffff0000u)};
        }

        float* zp = Z + ((size_t)b * LOUT + l) * UU + u0 + seg * 8;
        *(float4*)zp = make_float4(acc[0][0], acc[0][1], acc[1][0], acc[1][1]);
        *(float4*)(zp + 4) =
            make_float4(acc[2][0], acc[2][1], acc[3][0], acc[3][1]);
#pragma unroll
        for (int d = 0; d < 4; d++) {
          sm[d][0] = fmaxf(sm[d][0], acc[d][0]);
          sm[d][1] = fmaxf(sm[d][1], acc[d][1]);
        }
      }
    }

    // reduce max over the 8 lrow lanes (xor flips bits 3..5; seg preserved)
#pragma unroll
    for (int d = 0; d < 4; d++) {
#pragma unroll
      for (int off = 8; off <= 32; off <<= 1) {
        sm[d][0] = fmaxf(sm[d][0], __shfl_xor(sm[d][0], off));
        sm[d][1] = fmaxf(sm[d][1], __shfl_xor(sm[d][1], off));
      }
    }
    if (lrow == 0 && seg < nseg) {   // lanes 0..nseg-1 hold wave max for seg
      float* rp = pS2 + ((size_t)(b * 4 + wave)) * UU + u0 + seg * 8;
      *(float4*)rp = make_float4(sm[0][0], sm[0][1], sm[1][0], sm[1][1]);
      *(float4*)(rp + 4) = make_float4(sm[2][0], sm[2][1], sm[3][0], sm[3][1]);
    }
  }
}

// ---------------- kernel 4: S = max over f and waves of partial maxes ------
__global__ __launch_bounds__(256) void finalS(const float* __restrict__ pS2,
                                              float* __restrict__ S) {
  int i = blockIdx.x * 256 + threadIdx.x;
  if (i >= S_SIZE) return;
  int u = i % UU;
  int tn = i / UU;
  float m = -3.4e38f;
#pragma unroll
  for (int f = 0; f < 6; f++)
#pragma unroll
    for (int w = 0; w < 4; w++)
      m = fmaxf(m, pS2[((size_t)((tn * 6 + f) * 4 + w)) * UU + u]);
  S[i] = m;
}

extern "C" void kernel_launch(void* const* d_in, const int* in_sizes, int n_in,
                              void* d_out, int out_size, void* d_ws, size_t ws_size,
                              hipStream_t stream) {
  const float* X = (const float*)d_in[0];
  const float* P = (const float*)d_in[1];
  const float* Q = (const float*)d_in[2];
  float* S = (float*)d_out;
  float* R = S + S_SIZE;
  float* Z = R + R_SIZE;
  uint16_t* Rb = (uint16_t*)d_ws;
  uint8_t* ids = (uint8_t*)d_ws + WS_IDS_OFF;
  float* pS2 = (float*)((uint8_t*)d_ws + WS_PS_OFF);

  hipLaunchKernelGGL(prep_R, dim3((R_SIZE + 255) / 256), dim3(256), 0, stream,
                     P, Q, R, Rb);
  hipLaunchKernelGGL(prep_ids, dim3(NB), dim3(256), 0, stream, X, ids);
  hipLaunchKernelGGL(zmain, dim3(NB), dim3(256), 0, stream, Rb, ids, Z, pS2);
  hipLaunchKernelGGL(finalS, dim3((S_SIZE + 255) / 256), dim3(256), 0, stream,
                     pS2, S);
}